// Round 6
// baseline (145.604 us; speedup 1.0000x reference)
//
#include <hip/hip_runtime.h>
#include <hip/hip_fp16.h>
#include <float.h>

#define NC 64     // clusters
#define FD 128    // feature dim
#define LSTR 136  // LDS row stride in halfs (pad 16B)

typedef _Float16 f16x8 __attribute__((ext_vector_type(8)));
typedef _Float16 f16x4 __attribute__((ext_vector_type(4)));
typedef float f32x4 __attribute__((ext_vector_type(4)));

// ---------------- prep: fp16 cast, |x|^2, histogram, Mt build, S zero, out zero ----
__global__ void prep_kernel(const float* __restrict__ feat,
                            const int* __restrict__ labels,
                            float* __restrict__ sq,
                            unsigned short* __restrict__ Xh,
                            unsigned short* __restrict__ Mt,
                            float* __restrict__ S,
                            float* __restrict__ out, int out_size,
                            int* __restrict__ counts, int N) {
  __shared__ int hist[NC];
  int t = threadIdx.x;
  if (t < NC) hist[t] = 0;
  __syncthreads();
  int row = blockIdx.x * 32 + (t >> 3);
  int o = t & 7;
  if (row < N) {
    const float* rp = feat + (size_t)row * FD;
    float s = 0.f;
#pragma unroll
    for (int j = 0; j < 4; ++j) {
      int c4 = o + 8 * j;
      float4 v = *(const float4*)(rp + c4 * 4);
      ushort4 h;
      h.x = __half_as_ushort(__float2half(v.x));   // RNE
      h.y = __half_as_ushort(__float2half(v.y));
      h.z = __half_as_ushort(__float2half(v.z));
      h.w = __half_as_ushort(__float2half(v.w));
      *(ushort4*)&Xh[(size_t)row * FD + c4 * 4] = h;
      s = fmaf(v.x, v.x, s); s = fmaf(v.y, v.y, s);
      s = fmaf(v.z, v.z, s); s = fmaf(v.w, v.w, s);
    }
    s += __shfl_xor(s, 1); s += __shfl_xor(s, 2); s += __shfl_xor(s, 4);
    if (o == 0) { sq[row] = s; atomicAdd(&hist[labels[row]], 1); }
  }
  // zero S rows for this block (32 rows x NC floats = 8 floats/thread)
  if ((blockIdx.x + 1) * 32 <= N) {
    float4 z = {0.f, 0.f, 0.f, 0.f};
    size_t base = (size_t)blockIdx.x * 32 * NC + t * 8;
    *(float4*)&S[base] = z;
    *(float4*)&S[base + 4] = z;
  }
  if (blockIdx.x == 0 && t < out_size) out[t] = 0.f;
  // build Mt[n][col] = (labels[col]==n) ? 1.0h : 0  (8-col chunks)
  {
    int chunksPerN = N >> 3;
    int total = NC * chunksPerN;
    for (int id = blockIdx.x * 256 + t; id < total; id += gridDim.x * 256) {
      int n = id / chunksPerN;
      int c0 = (id - n * chunksPerN) * 8;
      ushort4 lo, hi;
      lo.x = (labels[c0 + 0] == n) ? 0x3C00 : 0;
      lo.y = (labels[c0 + 1] == n) ? 0x3C00 : 0;
      lo.z = (labels[c0 + 2] == n) ? 0x3C00 : 0;
      lo.w = (labels[c0 + 3] == n) ? 0x3C00 : 0;
      hi.x = (labels[c0 + 4] == n) ? 0x3C00 : 0;
      hi.y = (labels[c0 + 5] == n) ? 0x3C00 : 0;
      hi.z = (labels[c0 + 6] == n) ? 0x3C00 : 0;
      hi.w = (labels[c0 + 7] == n) ? 0x3C00 : 0;
      *(ushort4*)&Mt[(size_t)n * N + c0] = lo;
      *(ushort4*)&Mt[(size_t)n * N + c0 + 4] = hi;
    }
  }
  __syncthreads();
  if (t < NC) atomicAdd(&counts[t], hist[t]);
}

// ---------------- main: fp16 MFMA Gram + IN-REGISTER MFMA segment-sum --------------
// V7 = V6 (2 barriers/iter, in-reg S-pass, 2x2 wave grid, 2 blocks/CU) with the
// register squeeze removed. V6 evidence: VGPR_Count=128 + 128 acc = 256 = exactly
// the (256,2) cap -> 3.5MB spill residue + ILP-starved schedule -> 77us vs V1's 60
// at 216/256 regs. Fix: process the dist tile in TWO jb-pair passes -- dist-MFMA
// over 2 col-blocks (dacc[4][2] = 32 acc) then immediately epi+segment-sum them,
// then the next pair. Acc total 32+64=96 (V1's level), ~210/256 with headroom.
// Cost: af re-read once more per iter (+16 b128/wave, noise at 18% LDS util).
// Accumulation order per sacc reg unchanged -> bitwise-identical to V6 (absmax 0).
// Tripwire: WRITE_SIZE must be 32768 KB exactly; more means spill came back.
__global__ __launch_bounds__(256, 2)
void mfma_tile_kernel(const unsigned short* __restrict__ Xh,
                      const float* __restrict__ sq,
                      const unsigned short* __restrict__ Mt,
                      float* __restrict__ S,
                      int N, int colsPerSplit) {
  __shared__ __align__(16) unsigned short Ah[128 * LSTR];  // 34816 B, A resident
  __shared__ __align__(16) unsigned short Bh[128 * LSTR];  // 34816 B, B stage only

  const int t = threadIdx.x;
  const int R = blockIdx.x * 128;
  const int cBeg = blockIdx.y * colsPerSplit;
  const int wave = t >> 6, lane = t & 63;
  const int mm = lane & 15, quad = lane >> 4;
  const int wr = wave >> 1, wc = wave & 1;   // 2x2 wave grid, 64x64 tiles
  const int numTiles = colsPerSplit / 128;

  // stage A full-K: 2048 x 16B chunks over 256 threads (8 per thread)
#pragma unroll
  for (int it = 0; it < 8; ++it) {
    int c = t + it * 256;
    int r = c >> 4, k0 = (c & 15) * 8;
    *(uint4*)&Ah[r * LSTR + k0] = *(const uint4*)&Xh[(size_t)(R + r) * FD + k0];
  }

  // per-lane row |x|^2: with transposed output, row = lane&15 within each ib tile
  float sqi_r[4];
#pragma unroll
  for (int ib = 0; ib < 4; ++ib)
    sqi_r[ib] = sq[R + wr * 64 + ib * 16 + mm];

  f32x4 sacc[4][4];                          // S accum: [ib row-tile][label-tile]
#pragma unroll
  for (int ib = 0; ib < 4; ++ib)
#pragma unroll
    for (int lt = 0; lt < 4; ++lt) sacc[ib][lt] = (f32x4)0.f;

  for (int ct = 0; ct < numTiles; ++ct) {
    const int C0 = cBeg + ct * 128;
    __syncthreads();                         // WAR: prev dist reads of Bh done
#pragma unroll
    for (int it = 0; it < 8; ++it) {
      int c = t + it * 256;
      int r = c >> 4, k0 = (c & 15) * 8;
      *(uint4*)&Bh[r * LSTR + k0] = *(const uint4*)&Xh[(size_t)(C0 + r) * FD + k0];
    }
    __syncthreads();                         // RAW: Bh staged

    const bool hasDiag = (R == C0);

    // two jb-pair passes: dist-MFMA over 2 col-blocks, then epi+segment-sum them.
    // dacc live range = [4][2] = 32 acc regs instead of V6's 64.
#pragma unroll
    for (int jp = 0; jp < 2; ++jp) {
      // col |x|^2 for this pair (16B-aligned float4)
      float4 sjr[2];
#pragma unroll
      for (int j2 = 0; j2 < 2; ++j2)
        sjr[j2] = *(const float4*)&sq[C0 + wc * 64 + (jp * 2 + j2) * 16 + quad * 4];

      f32x4 dacc[4][2];                      // [ib][j2]
#pragma unroll
      for (int ib = 0; ib < 4; ++ib)
#pragma unroll
        for (int j2 = 0; j2 < 2; ++j2) dacc[ib][j2] = (f32x4)0.f;

#pragma unroll
      for (int ks = 0; ks < 4; ++ks) {
        const int ko = ks * 32 + quad * 8;
        f16x8 af[4], bf[2];
#pragma unroll
        for (int ib = 0; ib < 4; ++ib)
          af[ib] = *(const f16x8*)&Ah[(wr * 64 + ib * 16 + mm) * LSTR + ko];
#pragma unroll
        for (int j2 = 0; j2 < 2; ++j2)
          bf[j2] = *(const f16x8*)&Bh[(wc * 64 + (jp * 2 + j2) * 16 + mm) * LSTR + ko];
#pragma unroll
        for (int ib = 0; ib < 4; ++ib)
#pragma unroll
          for (int j2 = 0; j2 < 2; ++j2)
            dacc[ib][j2] = __builtin_amdgcn_mfma_f32_16x16x32_f16(bf[j2], af[ib], dacc[ib][j2], 0, 0, 0);
      }

      // epilogue + segment-sum for this pair, fully in registers, NO barriers:
      // d fragment (row=mm, cols quad*4+r of 16-col block jb) == A-frag of 16x16x16
#pragma unroll
      for (int j2 = 0; j2 < 2; ++j2) {
        const int jb = jp * 2 + j2;
        const int colBase = wc * 64 + jb * 16 + quad * 4;
        f16x4 mb[4];                         // Mt B-frags: lane(mm,quad) k=quad*4..+3
#pragma unroll
        for (int lt = 0; lt < 4; ++lt)
          mb[lt] = *(const f16x4*)&Mt[(size_t)(lt * 16 + mm) * N + C0 + colBase];
#pragma unroll
        for (int ib = 0; ib < 4; ++ib) {
          const int rowLocal = wr * 64 + ib * 16 + mm;
          const float si = sqi_r[ib];
          float d[4];
#pragma unroll
          for (int r = 0; r < 4; ++r) {
            float sj = (r == 0) ? sjr[j2].x : (r == 1) ? sjr[j2].y
                     : (r == 2) ? sjr[j2].z : sjr[j2].w;
            float d2 = fmaf(-2.f, dacc[ib][j2][r], si + sj);
            d[r] = __builtin_amdgcn_sqrtf(fmaxf(d2, 0.f));  // sqrt(0)=0: grad-safe
          }
          if (hasDiag) {                     // wave-uniform; 1 of numTiles iterations
#pragma unroll
            for (int r = 0; r < 4; ++r)
              if (rowLocal == colBase + r) d[r] = 0.f;
          }
          uint2 pk;
          pk.x = __builtin_bit_cast(unsigned, __builtin_amdgcn_cvt_pkrtz(d[0], d[1]));
          pk.y = __builtin_bit_cast(unsigned, __builtin_amdgcn_cvt_pkrtz(d[2], d[3]));
          f16x4 da = __builtin_bit_cast(f16x4, pk);
#pragma unroll
          for (int lt = 0; lt < 4; ++lt)
            sacc[ib][lt] = __builtin_amdgcn_mfma_f32_16x16x16f16(da, mb[lt], sacc[ib][lt], 0, 0, 0);
        }
      }
    }
  }

  // flush: wc-wave pairs and colSplit blocks merge via atomics
  // 16x16x16 C/D layout: col = mm (label), row = quad*4 + r within ib strip
#pragma unroll
  for (int ib = 0; ib < 4; ++ib)
#pragma unroll
    for (int lt = 0; lt < 4; ++lt)
#pragma unroll
      for (int r = 0; r < 4; ++r) {
        int rowD = wr * 64 + ib * 16 + quad * 4 + r;
        atomicAdd(&S[(size_t)(R + rowD) * NC + lt * 16 + mm], sacc[ib][lt][r]);
      }
}

// ---------------- score: a, b, silhouette, mean (vectorized) ----------------
__global__ void score_kernel(const float* __restrict__ S,
                             const int* __restrict__ labels,
                             const int* __restrict__ counts,
                             float* __restrict__ out, int N) {
  __shared__ float cnt_s[NC];
  __shared__ float inv_s[NC];
  __shared__ float red[128];
  int t = threadIdx.x;
  if (t < NC) {
    float c = (float)counts[t];
    cnt_s[t] = c;
    inv_s[t] = 1.f / fmaxf(c, 1.f);
  }
  __syncthreads();
  int i = blockIdx.x * 128 + t;
  float score = 0.f;
  if (i < N) {
    int li = labels[i];
    float own = cnt_s[li];
    const float4* Sv = (const float4*)(S + (size_t)i * NC);
    float a = S[(size_t)i * NC + li] / fmaxf(own - 1.f, 1.f);
    float b = FLT_MAX;
#pragma unroll
    for (int c4 = 0; c4 < NC / 4; ++c4) {
      float4 v = Sv[c4];
      int c = c4 * 4;
      float m0 = v.x * inv_s[c + 0];
      float m1 = v.y * inv_s[c + 1];
      float m2 = v.z * inv_s[c + 2];
      float m3 = v.w * inv_s[c + 3];
      b = fminf(b, (c + 0 == li || cnt_s[c + 0] == 0.f) ? FLT_MAX : m0);
      b = fminf(b, (c + 1 == li || cnt_s[c + 1] == 0.f) ? FLT_MAX : m1);
      b = fminf(b, (c + 2 == li || cnt_s[c + 2] == 0.f) ? FLT_MAX : m2);
      b = fminf(b, (c + 3 == li || cnt_s[c + 3] == 0.f) ? FLT_MAX : m3);
    }
    float mx = fmaxf(a, b);
    score = (own > 1.f) ? (b - a) / mx : 0.f;
  }
  red[t] = score;
  __syncthreads();
  for (int sft = 64; sft > 0; sft >>= 1) {
    if (t < sft) red[t] += red[t + sft];
    __syncthreads();
  }
  if (t == 0) atomicAdd(out, red[0] / (float)N);
}

extern "C" void kernel_launch(void* const* d_in, const int* in_sizes, int n_in,
                              void* d_out, int out_size, void* d_ws, size_t ws_size,
                              hipStream_t stream) {
  const float* feat = (const float*)d_in[0];
  const int* labels = (const int*)d_in[1];
  const int N = in_sizes[1];            // 8192; D=128, C=64 fixed by the reference
  float* out = (float*)d_out;
  char* ws = (char*)d_ws;

  // ws: counts(256B) | sq(N*4) | Xh(N*128*2) | Mt(64*N*2) | S(N*64*4)  ~5.03 MB @8192
  int*   counts = (int*)ws;
  float* sq     = (float*)(ws + 256);
  size_t o = 256 + (size_t)N * 4;
  o = (o + 255) & ~(size_t)255;
  unsigned short* Xh = (unsigned short*)(ws + o);                       // N*FD*2
  unsigned short* Mt = (unsigned short*)(ws + o + (size_t)N * FD * 2);  // NC*N*2
  float* S = (float*)(ws + o + (size_t)N * FD * 2 + (size_t)NC * N * 2);

  (void)hipMemsetAsync(counts, 0, 256, stream);

  prep_kernel<<<(N + 31) / 32, 256, 0, stream>>>(feat, labels, sq, Xh, Mt, S,
                                                 out, out_size, counts, N);

  const int colSplit = 8;               // 64 x 8 = 512 blocks = 2/CU (4 waves each)
  dim3 grid(N / 128, colSplit);
  mfma_tile_kernel<<<grid, 256, 0, stream>>>(Xh, sq, Mt, S, N, N / colSplit);

  score_kernel<<<(N + 127) / 128, 128, 0, stream>>>(S, labels, counts, out, N);
}

// Round 7
// 137.405 us; speedup vs baseline: 1.0597x; 1.0597x over previous
//
#include <hip/hip_runtime.h>
#include <hip/hip_fp16.h>
#include <float.h>

#define NC 64     // clusters
#define FD 128    // feature dim

typedef _Float16 f16x8 __attribute__((ext_vector_type(8)));
typedef float f32x4 __attribute__((ext_vector_type(4)));

// ---------------- prep: fp16 cast, |x|^2, histogram, Mt build, S zero, out zero ----
__global__ void prep_kernel(const float* __restrict__ feat,
                            const int* __restrict__ labels,
                            float* __restrict__ sq,
                            unsigned short* __restrict__ Xh,
                            unsigned short* __restrict__ Mt,
                            float* __restrict__ S,
                            float* __restrict__ out, int out_size,
                            int* __restrict__ counts, int N) {
  __shared__ int hist[NC];
  int t = threadIdx.x;
  if (t < NC) hist[t] = 0;
  __syncthreads();
  int row = blockIdx.x * 32 + (t >> 3);
  int o = t & 7;
  if (row < N) {
    const float* rp = feat + (size_t)row * FD;
    float s = 0.f;
#pragma unroll
    for (int j = 0; j < 4; ++j) {
      int c4 = o + 8 * j;
      float4 v = *(const float4*)(rp + c4 * 4);
      ushort4 h;
      h.x = __half_as_ushort(__float2half(v.x));   // RNE
      h.y = __half_as_ushort(__float2half(v.y));
      h.z = __half_as_ushort(__float2half(v.z));
      h.w = __half_as_ushort(__float2half(v.w));
      *(ushort4*)&Xh[(size_t)row * FD + c4 * 4] = h;
      s = fmaf(v.x, v.x, s); s = fmaf(v.y, v.y, s);
      s = fmaf(v.z, v.z, s); s = fmaf(v.w, v.w, s);
    }
    s += __shfl_xor(s, 1); s += __shfl_xor(s, 2); s += __shfl_xor(s, 4);
    if (o == 0) { sq[row] = s; atomicAdd(&hist[labels[row]], 1); }
  }
  // zero S rows for this block (32 rows x NC floats = 8 floats/thread)
  if ((blockIdx.x + 1) * 32 <= N) {
    float4 z = {0.f, 0.f, 0.f, 0.f};
    size_t base = (size_t)blockIdx.x * 32 * NC + t * 8;
    *(float4*)&S[base] = z;
    *(float4*)&S[base + 4] = z;
  }
  if (blockIdx.x == 0 && t < out_size) out[t] = 0.f;
  // build Mt[n][col] = (labels[col]==n) ? 1.0h : 0  (8-col chunks)
  {
    int chunksPerN = N >> 3;
    int total = NC * chunksPerN;
    for (int id = blockIdx.x * 256 + t; id < total; id += gridDim.x * 256) {
      int n = id / chunksPerN;
      int c0 = (id - n * chunksPerN) * 8;
      ushort4 lo, hi;
      lo.x = (labels[c0 + 0] == n) ? 0x3C00 : 0;
      lo.y = (labels[c0 + 1] == n) ? 0x3C00 : 0;
      lo.z = (labels[c0 + 2] == n) ? 0x3C00 : 0;
      lo.w = (labels[c0 + 3] == n) ? 0x3C00 : 0;
      hi.x = (labels[c0 + 4] == n) ? 0x3C00 : 0;
      hi.y = (labels[c0 + 5] == n) ? 0x3C00 : 0;
      hi.z = (labels[c0 + 6] == n) ? 0x3C00 : 0;
      hi.w = (labels[c0 + 7] == n) ? 0x3C00 : 0;
      *(ushort4*)&Mt[(size_t)n * N + c0] = lo;
      *(ushort4*)&Mt[(size_t)n * N + c0 + 4] = hi;
    }
  }
  __syncthreads();
  if (t < NC) atomicAdd(&counts[t], hist[t]);
}

// ---------------- main: fp16 MFMA Gram + LDS-D segment-sum, async DMA staging ------
// V8 = V1's proven phase structure (dist -> epi D in LDS -> 16x16x32 S-pass,
// 1x atomics; in-reg S-pass variants V6/V7 were 30% slower) with the storage
// engine rebuilt:
//  - A-frags in registers (64 VGPR, loaded once) -> Ah gone from LDS.
//  - Bh[2] double buffer (64KB, 2 blocks/CU) staged by global_load_lds width=16:
//    no VGPR round-trip, no ds_write issue; tile ct+1 prefetched at loop top so
//    its latency hides under dist instead of sitting exposed between barriers
//    (m233: that exposure is the dominant cost of 2-barrier stage loops).
//  - Barriers 4 -> 3/iter; __syncthreads' implicit vmcnt(0) lands the DMA.
//  - gload_lds writes linearly -> swizzle BOTH sides (rule #21): 16B-chunk idx
//    XOR (row&7) on the READ side, inverse-swizzled GLOBAL source on the write
//    side. Bank spread >= old LSTR=136 padding (2-way max, free).
// Math identical to V1 -> absmax must stay 0. Tripwires: WRITE_SIZE=16384KB
// exactly, LDS_Block_Size=65536, VGPR<=~125.
__device__ __forceinline__ int swz(int row, int chunk, int rem) {
  return row * 256 + ((chunk ^ (row & 7)) << 4) + rem;
}

__device__ __forceinline__ void gload_lds16(const unsigned short* g, unsigned short* l) {
  __builtin_amdgcn_global_load_lds(
      (const __attribute__((address_space(1))) void*)g,
      (__attribute__((address_space(3))) void*)l, 16, 0, 0);
}

__global__ __launch_bounds__(256, 2)
void mfma_tile_kernel(const unsigned short* __restrict__ Xh,
                      const float* __restrict__ sq,
                      const unsigned short* __restrict__ Mt,
                      float* __restrict__ S,
                      int N, int colsPerSplit) {
  __shared__ __align__(16) unsigned short Bh[2][128 * 128];  // 65536 B total

  const int t = threadIdx.x;
  const int R = blockIdx.x * 128;
  const int cBeg = blockIdx.y * colsPerSplit;
  const int wave = t >> 6, lane = t & 63;
  const int mm = lane & 15, quad = lane >> 4;
  const int wr = wave >> 1, wc = wave & 1;   // 2x2 wave grid, 64x64 tiles
  const int numTiles = colsPerSplit / 128;

  // async-stage one 128-row tile into Bh[buf]: linear DMA dest, inverse-swizzled
  // global source so that swizzled reads return logical data (m201 stage_rc).
#define STAGE(buf, C0base)                                                    \
  {                                                                           \
    const int rB_ = wave * 32;                                                \
    _Pragma("unroll")                                                         \
    for (int it_ = 0; it_ < 8; ++it_) {                                       \
      const int rloc_ = rB_ + it_ * 4 + (lane >> 4);                          \
      const int cch_ = lane & 15;                                             \
      const unsigned short* g_ =                                              \
          &Xh[(size_t)((C0base) + rloc_) * FD + ((cch_ ^ (rloc_ & 7)) << 3)]; \
      unsigned short* l_ = &Bh[buf][(size_t)(rB_ + it_ * 4) * 128];           \
      gload_lds16(g_, l_);                                                    \
    }                                                                         \
  }

  // ---- A fragments straight from global into registers (read once) ----
  f16x8 af[4][4];                            // [ib][ks], 64 VGPR
#pragma unroll
  for (int ib = 0; ib < 4; ++ib)
#pragma unroll
    for (int ks = 0; ks < 4; ++ks)
      af[ib][ks] = *(const f16x8*)&Xh[(size_t)(R + wr * 64 + ib * 16 + mm) * FD
                                      + ks * 32 + quad * 8];

  // per-lane row |x|^2: with transposed output, row = lane&15 within each ib tile
  float sqi_r[4];
#pragma unroll
  for (int ib = 0; ib < 4; ++ib)
    sqi_r[ib] = sq[R + wr * 64 + ib * 16 + mm];

  f32x4 sacc[2][4];                          // S accum: 2 row-tiles x 4 label-tiles
#pragma unroll
  for (int rt = 0; rt < 2; ++rt)
#pragma unroll
    for (int lt = 0; lt < 4; ++lt) sacc[rt][lt] = (f32x4)0.f;

  STAGE(0, cBeg);                            // tile 0
  __syncthreads();                           // implicit vmcnt(0) lands the DMA

  int cur = 0;
  for (int ct = 0; ct < numTiles; ++ct) {
    const int C0 = cBeg + ct * 128;
    if (ct + 1 < numTiles) STAGE(cur ^ 1, C0 + 128);  // async prefetch, no wait

    // col |x|^2: cols = quad*4 + r within each jb tile (transposed output layout)
    float sjr[4][4];
#pragma unroll
    for (int jb = 0; jb < 4; ++jb)
#pragma unroll
      for (int r = 0; r < 4; ++r)
        sjr[jb][r] = sq[C0 + wc * 64 + jb * 16 + quad * 4 + r];

    // Dist pass: operands swapped -> transposed C/D fragments
    f32x4 dacc[4][4];                        // [ib][jb]
#pragma unroll
    for (int ib = 0; ib < 4; ++ib)
#pragma unroll
      for (int jb = 0; jb < 4; ++jb) dacc[ib][jb] = (f32x4)0.f;

#pragma unroll
    for (int ks = 0; ks < 4; ++ks) {
      f16x8 bf[4];
#pragma unroll
      for (int jb = 0; jb < 4; ++jb) {
        const int rowB = wc * 64 + jb * 16 + mm;
        bf[jb] = *(const f16x8*)((const char*)&Bh[cur][0]
                                 + swz(rowB, ks * 4 + quad, 0));
      }
#pragma unroll
      for (int ib = 0; ib < 4; ++ib)
#pragma unroll
        for (int jb = 0; jb < 4; ++jb)
          dacc[ib][jb] = __builtin_amdgcn_mfma_f32_16x16x32_f16(bf[jb], af[ib][ks], dacc[ib][jb], 0, 0, 0);
    }
    __syncthreads();                         // dist reads of Bh[cur] done -> reuse as D
                                             // (also lands prefetch DMA; early but OK)

    // epilogue: lane holds row (lane&15), 4 contiguous cols (quad*4+r) -> D in LDS
    const bool hasDiag = (R == C0);
#pragma unroll
    for (int ib = 0; ib < 4; ++ib) {
      const int rowLocal = wr * 64 + ib * 16 + mm;
      const float si = sqi_r[ib];
#pragma unroll
      for (int jb = 0; jb < 4; ++jb) {
        const int colBase = wc * 64 + jb * 16 + quad * 4;
        float d[4];
#pragma unroll
        for (int r = 0; r < 4; ++r) {
          float d2 = fmaf(-2.f, dacc[ib][jb][r], si + sjr[jb][r]);
          d[r] = __builtin_amdgcn_sqrtf(fmaxf(d2, 0.f));  // sqrt(0)=0: grad-safe
        }
        if (hasDiag) {                       // wave-uniform; 1 of numTiles iterations
#pragma unroll
          for (int r = 0; r < 4; ++r)
            if (rowLocal == colBase + r) d[r] = 0.f;
        }
        uint2 pk;
        pk.x = __builtin_bit_cast(unsigned, __builtin_amdgcn_cvt_pkrtz(d[0], d[1]));
        pk.y = __builtin_bit_cast(unsigned, __builtin_amdgcn_cvt_pkrtz(d[2], d[3]));
        const int chunk = wc * 8 + jb * 2 + (quad >> 1);   // (2*colBase)>>4
        *(uint2*)((char*)&Bh[cur][0] + swz(rowLocal, chunk, (quad & 1) * 8)) = pk;
      }
    }
    __syncthreads();                         // D ready

    // S-pass: S_tile[128xNC] += D[128x128] x M[128xNC]; M frags from global Mt
#pragma unroll
    for (int ks = 0; ks < 4; ++ks) {
      const int r0 = wave * 32 + mm;
      f16x8 da0 = *(const f16x8*)((const char*)&Bh[cur][0] + swz(r0, ks * 4 + quad, 0));
      f16x8 da1 = *(const f16x8*)((const char*)&Bh[cur][0] + swz(r0 + 16, ks * 4 + quad, 0));
#pragma unroll
      for (int lt = 0; lt < 4; ++lt) {
        f16x8 mb = *(const f16x8*)&Mt[(size_t)(lt * 16 + mm) * N + C0 + ks * 32 + quad * 8];
        sacc[0][lt] = __builtin_amdgcn_mfma_f32_16x16x32_f16(da0, mb, sacc[0][lt], 0, 0, 0);
        sacc[1][lt] = __builtin_amdgcn_mfma_f32_16x16x32_f16(da1, mb, sacc[1][lt], 0, 0, 0);
      }
    }
    __syncthreads();                         // S-pass done -> Bh[cur] free for next prefetch
    cur ^= 1;
  }

  // flush: one atomic per S entry (only colSplit blocks contend per row)
#pragma unroll
  for (int rt = 0; rt < 2; ++rt)
#pragma unroll
    for (int lt = 0; lt < 4; ++lt)
#pragma unroll
      for (int r = 0; r < 4; ++r) {
        int row = wave * 32 + rt * 16 + quad * 4 + r;
        atomicAdd(&S[(size_t)(R + row) * NC + lt * 16 + mm], sacc[rt][lt][r]);
      }
#undef STAGE
}

// ---------------- score: a, b, silhouette, mean (vectorized) ----------------
__global__ void score_kernel(const float* __restrict__ S,
                             const int* __restrict__ labels,
                             const int* __restrict__ counts,
                             float* __restrict__ out, int N) {
  __shared__ float cnt_s[NC];
  __shared__ float inv_s[NC];
  __shared__ float red[128];
  int t = threadIdx.x;
  if (t < NC) {
    float c = (float)counts[t];
    cnt_s[t] = c;
    inv_s[t] = 1.f / fmaxf(c, 1.f);
  }
  __syncthreads();
  int i = blockIdx.x * 128 + t;
  float score = 0.f;
  if (i < N) {
    int li = labels[i];
    float own = cnt_s[li];
    const float4* Sv = (const float4*)(S + (size_t)i * NC);
    float a = S[(size_t)i * NC + li] / fmaxf(own - 1.f, 1.f);
    float b = FLT_MAX;
#pragma unroll
    for (int c4 = 0; c4 < NC / 4; ++c4) {
      float4 v = Sv[c4];
      int c = c4 * 4;
      float m0 = v.x * inv_s[c + 0];
      float m1 = v.y * inv_s[c + 1];
      float m2 = v.z * inv_s[c + 2];
      float m3 = v.w * inv_s[c + 3];
      b = fminf(b, (c + 0 == li || cnt_s[c + 0] == 0.f) ? FLT_MAX : m0);
      b = fminf(b, (c + 1 == li || cnt_s[c + 1] == 0.f) ? FLT_MAX : m1);
      b = fminf(b, (c + 2 == li || cnt_s[c + 2] == 0.f) ? FLT_MAX : m2);
      b = fminf(b, (c + 3 == li || cnt_s[c + 3] == 0.f) ? FLT_MAX : m3);
    }
    float mx = fmaxf(a, b);
    score = (own > 1.f) ? (b - a) / mx : 0.f;
  }
  red[t] = score;
  __syncthreads();
  for (int sft = 64; sft > 0; sft >>= 1) {
    if (t < sft) red[t] += red[t + sft];
    __syncthreads();
  }
  if (t == 0) atomicAdd(out, red[0] / (float)N);
}

extern "C" void kernel_launch(void* const* d_in, const int* in_sizes, int n_in,
                              void* d_out, int out_size, void* d_ws, size_t ws_size,
                              hipStream_t stream) {
  const float* feat = (const float*)d_in[0];
  const int* labels = (const int*)d_in[1];
  const int N = in_sizes[1];            // 8192; D=128, C=64 fixed by the reference
  float* out = (float*)d_out;
  char* ws = (char*)d_ws;

  // ws: counts(256B) | sq(N*4) | Xh(N*128*2) | Mt(64*N*2) | S(N*64*4)  ~5.03 MB @8192
  int*   counts = (int*)ws;
  float* sq     = (float*)(ws + 256);
  size_t o = 256 + (size_t)N * 4;
  o = (o + 255) & ~(size_t)255;
  unsigned short* Xh = (unsigned short*)(ws + o);                       // N*FD*2
  unsigned short* Mt = (unsigned short*)(ws + o + (size_t)N * FD * 2);  // NC*N*2
  float* S = (float*)(ws + o + (size_t)N * FD * 2 + (size_t)NC * N * 2);

  (void)hipMemsetAsync(counts, 0, 256, stream);

  prep_kernel<<<(N + 31) / 32, 256, 0, stream>>>(feat, labels, sq, Xh, Mt, S,
                                                 out, out_size, counts, N);

  const int colSplit = 8;               // 64 x 8 = 512 blocks = 2/CU (4 waves each)
  dim3 grid(N / 128, colSplit);
  mfma_tile_kernel<<<grid, 256, 0, stream>>>(Xh, sq, Mt, S, N, N / colSplit);

  score_kernel<<<(N + 127) / 128, 128, 0, stream>>>(S, labels, counts, out, N);
}

// Round 8
// 136.725 us; speedup vs baseline: 1.0649x; 1.0050x over previous
//
#include <hip/hip_runtime.h>
#include <hip/hip_fp16.h>
#include <float.h>

#define NC 64     // clusters
#define FD 128    // feature dim
#define LSTR 136  // LDS row stride in halfs (pad 16B)

typedef _Float16 f16x8 __attribute__((ext_vector_type(8)));
typedef float f32x4 __attribute__((ext_vector_type(4)));

// ---------------- prep: fp16 cast, |x|^2, histogram, Mt build, S zero, out zero ----
__global__ void prep_kernel(const float* __restrict__ feat,
                            const int* __restrict__ labels,
                            float* __restrict__ sq,
                            unsigned short* __restrict__ Xh,
                            unsigned short* __restrict__ Mt,
                            float* __restrict__ S,
                            float* __restrict__ out, int out_size,
                            int* __restrict__ counts, int N) {
  __shared__ int hist[NC];
  int t = threadIdx.x;
  if (t < NC) hist[t] = 0;
  __syncthreads();
  int row = blockIdx.x * 32 + (t >> 3);
  int o = t & 7;
  if (row < N) {
    const float* rp = feat + (size_t)row * FD;
    float s = 0.f;
#pragma unroll
    for (int j = 0; j < 4; ++j) {
      int c4 = o + 8 * j;
      float4 v = *(const float4*)(rp + c4 * 4);
      ushort4 h;
      h.x = __half_as_ushort(__float2half(v.x));   // RNE
      h.y = __half_as_ushort(__float2half(v.y));
      h.z = __half_as_ushort(__float2half(v.z));
      h.w = __half_as_ushort(__float2half(v.w));
      *(ushort4*)&Xh[(size_t)row * FD + c4 * 4] = h;
      s = fmaf(v.x, v.x, s); s = fmaf(v.y, v.y, s);
      s = fmaf(v.z, v.z, s); s = fmaf(v.w, v.w, s);
    }
    s += __shfl_xor(s, 1); s += __shfl_xor(s, 2); s += __shfl_xor(s, 4);
    if (o == 0) { sq[row] = s; atomicAdd(&hist[labels[row]], 1); }
  }
  // zero S rows for this block (32 rows x NC floats = 8 floats/thread)
  if ((blockIdx.x + 1) * 32 <= N) {
    float4 z = {0.f, 0.f, 0.f, 0.f};
    size_t base = (size_t)blockIdx.x * 32 * NC + t * 8;
    *(float4*)&S[base] = z;
    *(float4*)&S[base + 4] = z;
  }
  if (blockIdx.x == 0 && t < out_size) out[t] = 0.f;
  // build Mt[n][col] = (labels[col]==n) ? 1.0h : 0  (8-col chunks)
  {
    int chunksPerN = N >> 3;
    int total = NC * chunksPerN;
    for (int id = blockIdx.x * 256 + t; id < total; id += gridDim.x * 256) {
      int n = id / chunksPerN;
      int c0 = (id - n * chunksPerN) * 8;
      ushort4 lo, hi;
      lo.x = (labels[c0 + 0] == n) ? 0x3C00 : 0;
      lo.y = (labels[c0 + 1] == n) ? 0x3C00 : 0;
      lo.z = (labels[c0 + 2] == n) ? 0x3C00 : 0;
      lo.w = (labels[c0 + 3] == n) ? 0x3C00 : 0;
      hi.x = (labels[c0 + 4] == n) ? 0x3C00 : 0;
      hi.y = (labels[c0 + 5] == n) ? 0x3C00 : 0;
      hi.z = (labels[c0 + 6] == n) ? 0x3C00 : 0;
      hi.w = (labels[c0 + 7] == n) ? 0x3C00 : 0;
      *(ushort4*)&Mt[(size_t)n * N + c0] = lo;
      *(ushort4*)&Mt[(size_t)n * N + c0 + 4] = hi;
    }
  }
  __syncthreads();
  if (t < NC) atomicAdd(&counts[t], hist[t]);
}

// ---------------- main: fp16 MFMA Gram (operand-swapped) + MFMA segment-sum -------
// V9 = Round-0 V1 VERBATIM with exactly one change: A fragments live in registers
// (loaded once from global; bitwise-identical values to V1's Ah LDS reads), Ah
// removed from LDS. Unbundles V8's good idea from its three confounders (reg
// overshoot -> spill, DMA-barrier semantics, swizzle). Arch-VGPR peak ~115 < 128:
// af 64 + transient bf 32 + epi temps; no prefetch regs, no sjr-float4, classic
// ds_write staging with LSTR pad, same 4 barriers, same S-pass via D-in-Bh.
// Effects: dist LDS reads halve (32->16 b128/wave-iter, the largest pipe load),
// A staging gone, LDS 69632->34816 B.
// Tripwires: WRITE_SIZE must be 16384 KB exactly (no spill); LDS_Block_Size 34816.
__global__ __launch_bounds__(256, 2)
void mfma_tile_kernel(const unsigned short* __restrict__ Xh,
                      const float* __restrict__ sq,
                      const unsigned short* __restrict__ Mt,
                      float* __restrict__ S,
                      int N, int colsPerSplit) {
  __shared__ __align__(16) unsigned short Bh[128 * LSTR];  // 34816 B, B stage + D

  const int t = threadIdx.x;
  const int R = blockIdx.x * 128;
  const int cBeg = blockIdx.y * colsPerSplit;
  const int wave = t >> 6, lane = t & 63;
  const int mm = lane & 15, quad = lane >> 4;
  const int wr = wave >> 1, wc = wave & 1;   // 2x2 wave grid

  // A fragments once from global: same addresses V1 read from Ah, same values.
  f16x8 af[4][4];                            // [ib][ks], 64 VGPR, live all loop
#pragma unroll
  for (int ib = 0; ib < 4; ++ib)
#pragma unroll
    for (int ks = 0; ks < 4; ++ks)
      af[ib][ks] = *(const f16x8*)&Xh[(size_t)(R + wr * 64 + ib * 16 + mm) * FD
                                      + ks * 32 + quad * 8];

  // per-lane row |x|^2: with transposed output, row = lane&15 within each ib tile
  float sqi_r[4];
#pragma unroll
  for (int ib = 0; ib < 4; ++ib)
    sqi_r[ib] = sq[R + wr * 64 + ib * 16 + mm];

  f32x4 sacc[2][4];                          // S accum: 2 row-tiles x 4 label-tiles
#pragma unroll
  for (int rt = 0; rt < 2; ++rt)
#pragma unroll
    for (int lt = 0; lt < 4; ++lt) sacc[rt][lt] = (f32x4)0.f;

  const int numTiles = colsPerSplit / 128;
  for (int ct = 0; ct < numTiles; ++ct) {
    const int C0 = cBeg + ct * 128;
    __syncthreads();                         // prev S-pass done before Bh overwrite
#pragma unroll
    for (int it = 0; it < 8; ++it) {
      int c = t + it * 256;
      int r = c >> 4, k0 = (c & 15) * 8;
      *(uint4*)&Bh[r * LSTR + k0] = *(const uint4*)&Xh[(size_t)(C0 + r) * FD + k0];
    }
    // col |x|^2: cols = quad*4 + r within each jb tile (transposed output layout)
    float sjr[4][4];
#pragma unroll
    for (int jb = 0; jb < 4; ++jb)
#pragma unroll
      for (int r = 0; r < 4; ++r)
        sjr[jb][r] = sq[C0 + wc * 64 + jb * 16 + quad * 4 + r];
    __syncthreads();

    // Dist pass: operands swapped -> transposed C/D fragments
    f32x4 dacc[4][4];                        // [ib][jb]
#pragma unroll
    for (int ib = 0; ib < 4; ++ib)
#pragma unroll
      for (int jb = 0; jb < 4; ++jb) dacc[ib][jb] = (f32x4)0.f;

#pragma unroll
    for (int ks = 0; ks < 4; ++ks) {
      const int ko = ks * 32 + quad * 8;
      f16x8 bf[4];
#pragma unroll
      for (int jb = 0; jb < 4; ++jb)
        bf[jb] = *(const f16x8*)&Bh[(wc * 64 + jb * 16 + mm) * LSTR + ko];
#pragma unroll
      for (int ib = 0; ib < 4; ++ib)
#pragma unroll
        for (int jb = 0; jb < 4; ++jb)
          dacc[ib][jb] = __builtin_amdgcn_mfma_f32_16x16x32_f16(bf[jb], af[ib][ks], dacc[ib][jb], 0, 0, 0);
    }
    __syncthreads();                         // all waves done reading Bh -> reuse as D

    // epilogue: lane holds row (lane&15), 4 contiguous cols (quad*4+r)
    const bool hasDiag = (R == C0);
#pragma unroll
    for (int ib = 0; ib < 4; ++ib) {
      const int rowLocal = wr * 64 + ib * 16 + mm;
      const float si = sqi_r[ib];
#pragma unroll
      for (int jb = 0; jb < 4; ++jb) {
        const int colBase = wc * 64 + jb * 16 + quad * 4;
        float d[4];
#pragma unroll
        for (int r = 0; r < 4; ++r) {
          float d2 = fmaf(-2.f, dacc[ib][jb][r], si + sjr[jb][r]);
          d[r] = __builtin_amdgcn_sqrtf(fmaxf(d2, 0.f));  // sqrt(0)=0: grad-safe
        }
        if (hasDiag) {                       // wave-uniform; 1 of numTiles iterations
#pragma unroll
          for (int r = 0; r < 4; ++r)
            if (rowLocal == colBase + r) d[r] = 0.f;
        }
        uint2 pk;
        pk.x = __builtin_bit_cast(unsigned, __builtin_amdgcn_cvt_pkrtz(d[0], d[1]));
        pk.y = __builtin_bit_cast(unsigned, __builtin_amdgcn_cvt_pkrtz(d[2], d[3]));
        *(uint2*)&Bh[rowLocal * LSTR + colBase] = pk;    // 8B store, aligned
      }
    }
    __syncthreads();                         // D ready

    // S-pass: S_tile[128xNC] += D[128x128] x M[128xNC]; M frags from global Mt
#pragma unroll
    for (int ks = 0; ks < 4; ++ks) {
      const int ko = ks * 32 + quad * 8;
      f16x8 da0 = *(const f16x8*)&Bh[(wave * 32 + mm) * LSTR + ko];
      f16x8 da1 = *(const f16x8*)&Bh[(wave * 32 + 16 + mm) * LSTR + ko];
#pragma unroll
      for (int lt = 0; lt < 4; ++lt) {
        f16x8 mb = *(const f16x8*)&Mt[(size_t)(lt * 16 + mm) * N + C0 + ks * 32 + quad * 8];
        sacc[0][lt] = __builtin_amdgcn_mfma_f32_16x16x32_f16(da0, mb, sacc[0][lt], 0, 0, 0);
        sacc[1][lt] = __builtin_amdgcn_mfma_f32_16x16x32_f16(da1, mb, sacc[1][lt], 0, 0, 0);
      }
    }
  }

  // flush: one atomic per S entry (only colSplit blocks contend per row)
#pragma unroll
  for (int rt = 0; rt < 2; ++rt)
#pragma unroll
    for (int lt = 0; lt < 4; ++lt)
#pragma unroll
      for (int r = 0; r < 4; ++r) {
        int row = wave * 32 + rt * 16 + quad * 4 + r;
        atomicAdd(&S[(size_t)(R + row) * NC + lt * 16 + mm], sacc[rt][lt][r]);
      }
}

// ---------------- score: a, b, silhouette, mean (vectorized) ----------------
__global__ void score_kernel(const float* __restrict__ S,
                             const int* __restrict__ labels,
                             const int* __restrict__ counts,
                             float* __restrict__ out, int N) {
  __shared__ float cnt_s[NC];
  __shared__ float inv_s[NC];
  __shared__ float red[128];
  int t = threadIdx.x;
  if (t < NC) {
    float c = (float)counts[t];
    cnt_s[t] = c;
    inv_s[t] = 1.f / fmaxf(c, 1.f);
  }
  __syncthreads();
  int i = blockIdx.x * 128 + t;
  float score = 0.f;
  if (i < N) {
    int li = labels[i];
    float own = cnt_s[li];
    const float4* Sv = (const float4*)(S + (size_t)i * NC);
    float a = S[(size_t)i * NC + li] / fmaxf(own - 1.f, 1.f);
    float b = FLT_MAX;
#pragma unroll
    for (int c4 = 0; c4 < NC / 4; ++c4) {
      float4 v = Sv[c4];
      int c = c4 * 4;
      float m0 = v.x * inv_s[c + 0];
      float m1 = v.y * inv_s[c + 1];
      float m2 = v.z * inv_s[c + 2];
      float m3 = v.w * inv_s[c + 3];
      b = fminf(b, (c + 0 == li || cnt_s[c + 0] == 0.f) ? FLT_MAX : m0);
      b = fminf(b, (c + 1 == li || cnt_s[c + 1] == 0.f) ? FLT_MAX : m1);
      b = fminf(b, (c + 2 == li || cnt_s[c + 2] == 0.f) ? FLT_MAX : m2);
      b = fminf(b, (c + 3 == li || cnt_s[c + 3] == 0.f) ? FLT_MAX : m3);
    }
    float mx = fmaxf(a, b);
    score = (own > 1.f) ? (b - a) / mx : 0.f;
  }
  red[t] = score;
  __syncthreads();
  for (int sft = 64; sft > 0; sft >>= 1) {
    if (t < sft) red[t] += red[t + sft];
    __syncthreads();
  }
  if (t == 0) atomicAdd(out, red[0] / (float)N);
}

extern "C" void kernel_launch(void* const* d_in, const int* in_sizes, int n_in,
                              void* d_out, int out_size, void* d_ws, size_t ws_size,
                              hipStream_t stream) {
  const float* feat = (const float*)d_in[0];
  const int* labels = (const int*)d_in[1];
  const int N = in_sizes[1];            // 8192; D=128, C=64 fixed by the reference
  float* out = (float*)d_out;
  char* ws = (char*)d_ws;

  // ws: counts(256B) | sq(N*4) | Xh(N*128*2) | Mt(64*N*2) | S(N*64*4)  ~5.03 MB @8192
  int*   counts = (int*)ws;
  float* sq     = (float*)(ws + 256);
  size_t o = 256 + (size_t)N * 4;
  o = (o + 255) & ~(size_t)255;
  unsigned short* Xh = (unsigned short*)(ws + o);                       // N*FD*2
  unsigned short* Mt = (unsigned short*)(ws + o + (size_t)N * FD * 2);  // NC*N*2
  float* S = (float*)(ws + o + (size_t)N * FD * 2 + (size_t)NC * N * 2);

  (void)hipMemsetAsync(counts, 0, 256, stream);

  prep_kernel<<<(N + 31) / 32, 256, 0, stream>>>(feat, labels, sq, Xh, Mt, S,
                                                 out, out_size, counts, N);

  const int colSplit = 8;               // 64 x 8 = 512 blocks = 2/CU (4 waves each)
  dim3 grid(N / 128, colSplit);
  mfma_tile_kernel<<<grid, 256, 0, stream>>>(Xh, sq, Mt, S, N, N / colSplit);

  score_kernel<<<(N + 127) / 128, 128, 0, stream>>>(S, labels, counts, out, N);
}